// Round 1
// 209.282 us; speedup vs baseline: 1.1036x; 1.1036x over previous
//
#include <hip/hip_runtime.h>
#include <hip/hip_fp16.h>
#include <hip/hip_bf16.h>
#include <math.h>

#define NEG_SLOPE 0.2f
#define BN_EPS 1e-5f

typedef short  bf16x8 __attribute__((ext_vector_type(8)));
typedef float  f32x4  __attribute__((ext_vector_type(4)));

__device__ __forceinline__ float leaky(float v) {
    return v > 0.0f ? v : NEG_SLOPE * v;
}

__device__ __forceinline__ short bfbits(float f) {
    __hip_bfloat16 h = __float2bfloat16(f);
    return __builtin_bit_cast(short, h);
}

__device__ __forceinline__ bf16x8 cvt8(const float* p) {
    float4 u = *(const float4*)p;
    float4 v = *(const float4*)(p + 4);
    bf16x8 a;
    a[0] = bfbits(u.x); a[1] = bfbits(u.y); a[2] = bfbits(u.z); a[3] = bfbits(u.w);
    a[4] = bfbits(v.x); a[5] = bfbits(v.y); a[6] = bfbits(v.z); a[7] = bfbits(v.w);
    return a;
}

// ======== FUSED: ELL build + MFMA GEMM in one dispatch ========
// The two phases have zero data dependency (deg is zeroed by hipMemsetAsync
// before this launch). Block roles interleave round-robin (R edge-blocks per
// 1 gemm-block, R = ceil(edge_blocks/gemm_blocks)) so every CU hosts a mix:
// the latency-bound edge waves (load -> atomicAdd -> scatter, ~0.8% VALU)
// hide under the GEMM's MFMA + VMEM stream instead of serializing after it.
// Edge path is 1 edge/thread (vs 4 before): 4x the wave count of old k_ell,
// which was grid-starved at 26% occupancy / 3 waves-per-SIMD.
// Self-loops stay synthesized analytically in k_node (slot deg), tickets
// clamp at 63.
__global__ __launch_bounds__(256) void k_gemm_ell(
    const float* __restrict__ x, const float* __restrict__ w,
    __half2* __restrict__ h2, const float* __restrict__ att_s,
    const float* __restrict__ att_d, float* __restrict__ a_src,
    float* __restrict__ a_dst, int* __restrict__ deg,
    int* __restrict__ ell, const int* __restrict__ esrc,
    const int* __restrict__ edst, int n, int E, int R)
{
    const int role = blockIdx.x % (R + 1);
    if (role != R) {
        // ---- edge path: one real edge per thread ----
        int e_blk = (blockIdx.x / (R + 1)) * R + role;
        int m = e_blk * 256 + threadIdx.x;
        if (m < E) {
            int s = esrc[m];
            int d = edst[m];
            int o = atomicAdd(&deg[d], 1);
            if (o < 63) ell[(size_t)d * 64 + o] = s;
        }
        return;
    }

    // ---- gemm path: one wave = 16 rows x 128 cols, no LDS ----
    const int bb = blockIdx.x / (R + 1);
    const int t = threadIdx.x;
    const int wave = t >> 6;
    const int lane = t & 63;
    const int m = lane & 15;
    const int quad = lane >> 4;
    const int r0w = bb * 64 + wave * 16;

    f32x4 acc[8];
    #pragma unroll
    for (int g = 0; g < 8; ++g) acc[g] = (f32x4){0.f, 0.f, 0.f, 0.f};

    const int arow = min(r0w + m, n - 1);
    const float* xrow = x + (size_t)arow * 128 + quad * 8;

    #pragma unroll
    for (int k0 = 0; k0 < 4; ++k0) {
        bf16x8 a = cvt8(xrow + k0 * 32);
        #pragma unroll
        for (int g = 0; g < 8; ++g) {
            bf16x8 b = cvt8(&w[(size_t)(16 * g + m) * 128 + k0 * 32 + quad * 8]);
            acc[g] = __builtin_amdgcn_mfma_f32_16x16x32_bf16(a, b, acc[g], 0, 0, 0);
        }
    }

    float asv[8], adv[8];
    #pragma unroll
    for (int g = 0; g < 8; ++g) {
        asv[g] = att_s[16 * g + m];
        adv[g] = att_d[16 * g + m];
    }
    float ss[4][4], sd[4][4];          // [reg][head]
    #pragma unroll
    for (int reg = 0; reg < 4; ++reg) {
        #pragma unroll
        for (int h = 0; h < 4; ++h) {
            float ps = acc[2 * h][reg] * asv[2 * h] + acc[2 * h + 1][reg] * asv[2 * h + 1];
            float pd = acc[2 * h][reg] * adv[2 * h] + acc[2 * h + 1][reg] * adv[2 * h + 1];
            #pragma unroll
            for (int msk = 1; msk <= 8; msk <<= 1) {
                ps += __shfl_xor(ps, msk, 64);
                pd += __shfl_xor(pd, msk, 64);
            }
            ss[reg][h] = ps; sd[reg][h] = pd;
        }
    }
    if (m == 0) {
        #pragma unroll
        for (int reg = 0; reg < 4; ++reg) {
            int grow = r0w + quad * 4 + reg;
            if (grow < n) {
                ((float4*)a_src)[grow] = make_float4(ss[reg][0], ss[reg][1], ss[reg][2], ss[reg][3]);
                ((float4*)a_dst)[grow] = make_float4(sd[reg][0], sd[reg][1], sd[reg][2], sd[reg][3]);
            }
        }
    }

    #pragma unroll
    for (int reg = 0; reg < 4; ++reg) {
        int grow = r0w + quad * 4 + reg;
        #pragma unroll
        for (int g = 0; g < 8; ++g) {
            float v0 = acc[g][reg];
            float v1 = __shfl_xor(v0, 1, 64);
            if (!(m & 1) && grow < n)
                h2[(size_t)grow * 64 + 8 * g + (m >> 1)] = __floats2half2_rn(v0, v1);
        }
    }
}

// ======== per-node softmax + aggregate + bias + BN-partials. Grid-stride. ====
// salpha stride 72 (72%32==8): gather-read bank = 8*head+g -> 16 distinct banks
// (stride 65 gave only 7 banks for 16 groups -> the 462k conflicts of R10).
// Gather loop now processes 16 slots/iteration (4 independent load chains,
// doubled from 2): k_node was at 33% HBM / 42% VALU — neither roofline —
// i.e. gather-latency bound; 2x MLP attacks that directly. Padding slots are
// nearly free: lanes >= degT hold myS=0, so padded gathers re-read node 0's
// row (L1-hot) and their alpha is exactly 0.
// All shfl sites run with all 64 lanes active (R7 lesson).
// Every lane ends with the reduced 8 channels -> accumulate raw sum/sumsq in
// regs across the node stride; block-reduce into pbuf (bias folded in later).
__global__ __launch_bounds__(256) void k_node(
    const int* __restrict__ degA, const int* __restrict__ ell,
    const float* __restrict__ a_src, const float* __restrict__ a_dst,
    const __half2* __restrict__ h2, const float* __restrict__ bias,
    float* __restrict__ out, float* __restrict__ pbuf, int n)
{
    __shared__ float salpha[4][4][72];
    __shared__ float pb[4][256];
    const int wv = threadIdx.x >> 6;
    const int lane = threadIdx.x & 63;
    const int g  = lane >> 4;
    const int c4 = lane & 15;
    const int head = c4 >> 2;
    const float* ap = &salpha[wv][head][0];
    const float4* h4 = (const float4*)h2;
    const float4 b0 = ((const float4*)bias)[2 * c4];
    const float4 b1 = ((const float4*)bias)[2 * c4 + 1];
    const int stride = gridDim.x * 4;

    float s8[8], q8[8];
    #pragma unroll
    for (int j = 0; j < 8; ++j) { s8[j] = 0.f; q8[j] = 0.f; }

    for (int d = blockIdx.x * 4 + wv; d < n; d += stride) {
        const int deg = min(degA[d], 63);
        const int degT = deg + 1;                  // + synthesized self-loop
        const float4 ad = ((const float4*)a_dst)[d];

        int myS = 0;
        float4 ex = make_float4(0.f, 0.f, 0.f, 0.f);
        if (lane < degT) {
            myS = (lane < deg) ? ell[(size_t)d * 64 + lane] : d;
            float4 as = ((const float4*)a_src)[myS];
            ex = make_float4(__expf(leaky(as.x + ad.x)), __expf(leaky(as.y + ad.y)),
                             __expf(leaky(as.z + ad.z)), __expf(leaky(as.w + ad.w)));
        }
        float4 sm = ex;
        #pragma unroll
        for (int m = 32; m >= 1; m >>= 1) {
            sm.x += __shfl_xor(sm.x, m, 64);
            sm.y += __shfl_xor(sm.y, m, 64);
            sm.z += __shfl_xor(sm.z, m, 64);
            sm.w += __shfl_xor(sm.w, m, 64);
        }
        salpha[wv][0][lane] = ex.x / (sm.x + 1e-16f);   // 0 beyond degT
        salpha[wv][1][lane] = ex.y / (sm.y + 1e-16f);
        salpha[wv][2][lane] = ex.z / (sm.z + 1e-16f);
        salpha[wv][3][lane] = ex.w / (sm.w + 1e-16f);
        // wave-private LDS: lgkmcnt ordering suffices, no barrier

        float2 a0 = {0.f, 0.f}, a1 = {0.f, 0.f}, a2 = {0.f, 0.f}, a3 = {0.f, 0.f};
#define ACC4(hv, al)                                                         \
        do {                                                                 \
            float2 f0 = __half22float2(__builtin_bit_cast(__half2, hv.x));   \
            float2 f1 = __half22float2(__builtin_bit_cast(__half2, hv.y));   \
            float2 f2 = __half22float2(__builtin_bit_cast(__half2, hv.z));   \
            float2 f3 = __half22float2(__builtin_bit_cast(__half2, hv.w));   \
            a0.x += f0.x * al; a0.y += f0.y * al;                            \
            a1.x += f1.x * al; a1.y += f1.y * al;                            \
            a2.x += f2.x * al; a2.y += f2.y * al;                            \
            a3.x += f3.x * al; a3.y += f3.y * al;                            \
        } while (0)

        for (int kk0 = 0; kk0 < degT; kk0 += 16) {  // wave-uniform; kk0 <= 48
            int kA = kk0 + g;                       // <= 51
            int kB = kk0 + 4 + g;                   // <= 55
            int kC = kk0 + 8 + g;                   // <= 59
            int kD = kk0 + 12 + g;                  // <= 63
            int sA = __shfl(myS, kA, 64);
            int sB = __shfl(myS, kB, 64);
            int sC = __shfl(myS, kC, 64);
            int sD = __shfl(myS, kD, 64);
            float alA = ap[kA];                     // 0 for k >= degT
            float alB = ap[kB];
            float alC = ap[kC];
            float alD = ap[kD];
            float4 hA = h4[(unsigned)(sA * 16 + c4)];
            float4 hB = h4[(unsigned)(sB * 16 + c4)];
            float4 hC = h4[(unsigned)(sC * 16 + c4)];
            float4 hD = h4[(unsigned)(sD * 16 + c4)];
            ACC4(hA, alA);
            ACC4(hB, alB);
            ACC4(hC, alC);
            ACC4(hD, alD);
        }
#undef ACC4
        #pragma unroll
        for (int msk = 16; msk <= 32; msk <<= 1) {
            a0.x += __shfl_xor(a0.x, msk, 64); a0.y += __shfl_xor(a0.y, msk, 64);
            a1.x += __shfl_xor(a1.x, msk, 64); a1.y += __shfl_xor(a1.y, msk, 64);
            a2.x += __shfl_xor(a2.x, msk, 64); a2.y += __shfl_xor(a2.y, msk, 64);
            a3.x += __shfl_xor(a3.x, msk, 64); a3.y += __shfl_xor(a3.y, msk, 64);
        }
        s8[0] += a0.x; q8[0] += a0.x * a0.x;
        s8[1] += a0.y; q8[1] += a0.y * a0.y;
        s8[2] += a1.x; q8[2] += a1.x * a1.x;
        s8[3] += a1.y; q8[3] += a1.y * a1.y;
        s8[4] += a2.x; q8[4] += a2.x * a2.x;
        s8[5] += a2.y; q8[5] += a2.y * a2.y;
        s8[6] += a3.x; q8[6] += a3.x * a3.x;
        s8[7] += a3.y; q8[7] += a3.y * a3.y;

        if (g == 0) {
            ((float4*)out)[(size_t)d * 32 + 2 * c4] =
                make_float4(a0.x + b0.x, a0.y + b0.y, a1.x + b0.z, a1.y + b0.w);
        } else if (g == 1) {
            ((float4*)out)[(size_t)d * 32 + 2 * c4 + 1] =
                make_float4(a2.x + b1.x, a2.y + b1.y, a3.x + b1.z, a3.y + b1.w);
        }
    }

    // block reduction of BN partials -> pbuf[block][256] (128 sum | 128 sumsq)
    if (g == 0) {
        #pragma unroll
        for (int j = 0; j < 8; ++j) {
            pb[wv][8 * c4 + j]       = s8[j];
            pb[wv][128 + 8 * c4 + j] = q8[j];
        }
    }
    __syncthreads();
    {
        int t = threadIdx.x;
        float v = pb[0][t] + pb[1][t] + pb[2][t] + pb[3][t];
        pbuf[(size_t)blockIdx.x * 256 + t] = v;
    }
}

// ======== BN reduce: 128 blocks (one per channel) over pbuf partials ========
// sums/sumsq include the bias shift analytically: out = agg + b.
__global__ __launch_bounds__(256) void k_bn_reduce(
    const float* __restrict__ pbuf, const float* __restrict__ bias,
    float* __restrict__ sums, float* __restrict__ sumsq, int nb2, int n)
{
    __shared__ float ls[256], lq[256];
    const int c = blockIdx.x;
    const int t = threadIdx.x;
    float S = 0.f, Q = 0.f;
    for (int b = t; b < nb2; b += 256) {
        S += pbuf[(size_t)b * 256 + c];
        Q += pbuf[(size_t)b * 256 + 128 + c];
    }
    ls[t] = S; lq[t] = Q;
    __syncthreads();
    for (int off = 128; off >= 1; off >>= 1) {
        if (t < off) { ls[t] += ls[t + off]; lq[t] += lq[t + off]; }
        __syncthreads();
    }
    if (t == 0) {
        float b_ = bias[c];
        float Sr = ls[0], Qr = lq[0];
        sums[c]  = Sr + (float)n * b_;
        sumsq[c] = Qr + 2.f * b_ * Sr + (float)n * b_ * b_;
    }
}

// ======== BN apply + ReLU ========
__global__ __launch_bounds__(256) void k_bn_apply(
    float* __restrict__ out, const float* __restrict__ sums,
    const float* __restrict__ sumsq, const float* __restrict__ gamma,
    const float* __restrict__ beta, int n, int total)
{
    int i = blockIdx.x * 256 + threadIdx.x;
    if (i >= total) return;
    int c = i & 127;
    float invn = 1.0f / (float)n;
    float mean = sums[c] * invn;
    float var = sumsq[c] * invn - mean * mean;
    float v = out[i];
    float y = (v - mean) * rsqrtf(var + BN_EPS) * gamma[c] + beta[c];
    out[i] = fmaxf(y, 0.0f);
}

extern "C" void kernel_launch(void* const* d_in, const int* in_sizes, int n_in,
                              void* d_out, int out_size, void* d_ws, size_t ws_size,
                              hipStream_t stream)
{
    const float* x     = (const float*)d_in[0];
    const int*   ei    = (const int*)d_in[1];
    const float* w     = (const float*)d_in[2];
    const float* att_s = (const float*)d_in[3];
    const float* att_d = (const float*)d_in[4];
    const float* bias  = (const float*)d_in[5];
    const float* gamma = (const float*)d_in[6];
    const float* beta  = (const float*)d_in[7];

    const int n = in_sizes[0] / 128;
    const int E = in_sizes[1] / 2;
    const int total = n * 128;
    float* out = (float*)d_out;

    // ws layout (~29.5 MB, inside the proven envelope):
    // h2[n*64] half2 | a_src[n*4] f | a_dst[n*4] f | deg[n] i |
    // sums[128] f | sumsq[128] f | ell[n*64] i | pbuf[nb2*256] f
    float*   ws    = (float*)d_ws;
    __half2* h2    = (__half2*)ws;
    float*   a_src = ws + (size_t)n * 64;
    float*   a_dst = a_src + (size_t)n * 4;
    int*     deg   = (int*)(a_dst + (size_t)n * 4);
    float*   sums  = (float*)(deg + n);
    float*   sumsq = sums + 128;
    int*     ell   = (int*)(sumsq + 128);
    float*   pbuf  = (float*)(ell + (size_t)n * 64);

    const int* esrc = ei;
    const int* edst = ei + E;

    const int gb  = (n + 63) / 64;              // gemm blocks
    const int eb1 = (E + 255) / 256;            // edge blocks (1 edge/thread)
    const int R   = (eb1 + gb - 1) / gb;        // edge blocks per gemm block
    const int fused_blocks = gb * (R + 1);      // interleaved roles, period R+1
    const int nb2 = min(2048, (n + 3) / 4);     // k_node blocks (grid-stride)

    hipMemsetAsync(deg, 0, (size_t)n * sizeof(int), stream);
    k_gemm_ell<<<fused_blocks, 256, 0, stream>>>(x, w, h2, att_s, att_d,
                                                 a_src, a_dst, deg, ell,
                                                 esrc, edst, n, E, R);
    k_node<<<nb2, 256, 0, stream>>>(deg, ell, a_src, a_dst, h2, bias, out, pbuf, n);
    k_bn_reduce<<<128, 256, 0, stream>>>(pbuf, bias, sums, sumsq, nb2, n);
    k_bn_apply<<<(total + 255) / 256, 256, 0, stream>>>(out, sums, sumsq, gamma, beta, n, total);
}